// Round 4
// baseline (474.845 us; speedup 1.0000x reference)
//
#include <hip/hip_runtime.h>
#include <math.h>

#define BATCH 64
#define SLATES 25
#define KPS 20
#define EDIM 256
#define DDIM 512
#define HEADS 8
#define HD 64
#define LFULL 501
#define NROWS 500
#define MTOT (BATCH*NROWS)   // 32000

typedef __attribute__((ext_vector_type(8))) short short8;
typedef __attribute__((ext_vector_type(4))) float f32x4;

__device__ __forceinline__ unsigned short f2bf(float x) {
    unsigned int u = __builtin_bit_cast(unsigned int, x);
    u = (u + 0x7FFFu + ((u >> 16) & 1u)) >> 16;
    return (unsigned short)u;
}
__device__ __forceinline__ float bf2f(unsigned short s) {
    unsigned int u = ((unsigned int)s) << 16;
    return __builtin_bit_cast(float, u);
}
__device__ __forceinline__ float gelu_exact(float x) {
    return 0.5f * x * (1.0f + erff(x * 0.70710678118654752440f));
}

// ---------------------------------------------------------------------------
// fp32 -> bf16 converts
// ---------------------------------------------------------------------------
__global__ __launch_bounds__(256) void cvt_kernel(
    const float* __restrict__ src, unsigned short* __restrict__ dst, int n4)
{
    const int i = blockIdx.x * 256 + threadIdx.x;
    if (i >= n4) return;
    float4 v = ((const float4*)src)[i];
    ushort4 o;
    o.x = f2bf(v.x); o.y = f2bf(v.y); o.z = f2bf(v.z); o.w = f2bf(v.w);
    ((ushort4*)dst)[i] = o;
}

struct Cvt5 { const float* s[5]; unsigned short* d[5]; };
__global__ __launch_bounds__(256) void cvt5_kernel(Cvt5 a, int n4)
{
    const int i = blockIdx.x * 256 + threadIdx.x;
    if (i >= n4) return;
    const int y = blockIdx.y;
    float4 v = ((const float4*)a.s[y])[i];
    ushort4 o;
    o.x = f2bf(v.x); o.y = f2bf(v.y); o.z = f2bf(v.z); o.w = f2bf(v.w);
    ((ushort4*)a.d[y])[i] = o;
}

// ---------------------------------------------------------------------------
// Per-batch user-projection bias tables (fp32) + row0 of q/k (head-major) and
// v (transposed (B,H,64,L) layout).
// ---------------------------------------------------------------------------
__global__ __launch_bounds__(256) void user_bias_kernel(
    const float* __restrict__ user,
    const float* __restrict__ Wq, const float* __restrict__ bq,
    const float* __restrict__ Wk, const float* __restrict__ bk,
    const float* __restrict__ Wv, const float* __restrict__ bv,
    float* __restrict__ ubq, float* __restrict__ ubk, float* __restrict__ ubv,
    unsigned short* __restrict__ qb, unsigned short* __restrict__ kb,
    unsigned short* __restrict__ vt)
{
    const int b = blockIdx.x;
    const int y = blockIdx.y;
    const int tid = threadIdx.x;
    const float* W  = (y == 0) ? Wq : (y == 1) ? Wk : Wv;
    const float* bi = (y == 0) ? bq : (y == 1) ? bk : bv;
    float* ub = (y == 0) ? ubq : (y == 1) ? ubk : ubv;

    __shared__ float us[EDIM];
    if (tid < EDIM) us[tid] = user[b * EDIM + tid];
    __syncthreads();
    for (int o = tid; o < DDIM; o += 256) {
        float s = bi[o];
        const float* wr = &W[(size_t)o * DDIM + EDIM];
#pragma unroll 4
        for (int e = 0; e < EDIM; ++e) s += us[e] * wr[e];
        ub[b * DDIM + o] = s;
        const int hh = o >> 6, dd = o & 63;
        const size_t bh = (size_t)b * HEADS + hh;
        if (y == 0)      qb[(bh * LFULL) * HD + dd] = f2bf(bi[o]);
        else if (y == 1) kb[(bh * LFULL) * HD + dd] = f2bf(bi[o]);
        else             vt[(bh * HD + dd) * LFULL] = f2bf(bi[o]);
    }
}

// ---------------------------------------------------------------------------
// Fused QKV GEMM. q/k out: head-major (B,H,501,64), row l=m%500+1.
// v out: transposed (B,H,64,501). blockIdx.z picks q/k/v.
// ---------------------------------------------------------------------------
__global__ __launch_bounds__(256) void gemm_qkv(
    const unsigned short* __restrict__ A,
    const unsigned short* __restrict__ Wq, const unsigned short* __restrict__ Wk,
    const unsigned short* __restrict__ Wv,
    const float* __restrict__ uq, const float* __restrict__ uk,
    const float* __restrict__ uv,
    unsigned short* __restrict__ oq, unsigned short* __restrict__ ok,
    unsigned short* __restrict__ ov)
{
    const int z = blockIdx.z;
    const unsigned short* W = (z == 0) ? Wq : (z == 1) ? Wk : Wv;
    const float* ub = (z == 0) ? uq : (z == 1) ? uk : uv;
    unsigned short* outp = (z == 0) ? oq : (z == 1) ? ok : ov;

    const int tid = threadIdx.x;
    const int n0 = blockIdx.x * 128;
    const int m0 = blockIdx.y * 128;
    const int lane = tid & 63, wid = tid >> 6;
    const int wm = (wid & 1) * 64, wn = (wid >> 1) * 64;

    __shared__ unsigned short As[128][40];
    __shared__ unsigned short Ws[128][40];

    f32x4 acc[4][4];
#pragma unroll
    for (int i = 0; i < 4; ++i)
#pragma unroll
        for (int j = 0; j < 4; ++j) acc[i][j] = (f32x4){0.f, 0.f, 0.f, 0.f};

    const int srow = tid >> 1, sseg = (tid & 1) * 16;
    const unsigned short* gA = &A[(size_t)(m0 + srow) * EDIM + sseg];
    const unsigned short* gW = &W[(size_t)(n0 + srow) * DDIM + sseg];
    const int frow = lane & 15, fk = (lane >> 4) * 8;

    for (int k0 = 0; k0 < EDIM; k0 += 32) {
        uint4 a0 = *(const uint4*)(gA + k0);
        uint4 a1 = *(const uint4*)(gA + k0 + 8);
        uint4 w0 = *(const uint4*)(gW + k0);
        uint4 w1 = *(const uint4*)(gW + k0 + 8);
        __syncthreads();
        *(uint4*)&As[srow][sseg]     = a0;
        *(uint4*)&As[srow][sseg + 8] = a1;
        *(uint4*)&Ws[srow][sseg]     = w0;
        *(uint4*)&Ws[srow][sseg + 8] = w1;
        __syncthreads();
        short8 af[4], wf[4];
#pragma unroll
        for (int mi = 0; mi < 4; ++mi)
            af[mi] = *(const short8*)&As[wm + mi * 16 + frow][fk];
#pragma unroll
        for (int ni = 0; ni < 4; ++ni)
            wf[ni] = *(const short8*)&Ws[wn + ni * 16 + frow][fk];
#pragma unroll
        for (int mi = 0; mi < 4; ++mi)
#pragma unroll
            for (int ni = 0; ni < 4; ++ni)
                acc[mi][ni] = __builtin_amdgcn_mfma_f32_16x16x32_bf16(
                    af[mi], wf[ni], acc[mi][ni], 0, 0, 0);
    }

#pragma unroll
    for (int mi = 0; mi < 4; ++mi) {
#pragma unroll
        for (int ni = 0; ni < 4; ++ni) {
            const int n = n0 + wn + ni * 16 + (lane & 15);
            const int hh = n >> 6, dd = n & 63;
#pragma unroll
            for (int r = 0; r < 4; ++r) {
                const int m = m0 + wm + mi * 16 + (lane >> 4) * 4 + r;
                const int b = m / NROWS;
                const int l = m - b * NROWS + 1;
                const size_t bh = (size_t)b * HEADS + hh;
                const float v = acc[mi][ni][r] + ub[(size_t)b * DDIM + n];
                if (z == 2)
                    outp[(bh * HD + dd) * LFULL + l] = f2bf(v);
                else
                    outp[(bh * LFULL + l) * HD + dd] = f2bf(v);
            }
        }
    }
}

// ---------------------------------------------------------------------------
// Generic bf16 GEMM for Wo / W1 stages.
// MODE 1: +bias, fp32 out. MODE 2: +bias + gelu, bf16 out.
// ---------------------------------------------------------------------------
template <int MODE>
__global__ __launch_bounds__(256) void gemm_bf16(
    const unsigned short* __restrict__ A,
    const unsigned short* __restrict__ W,
    const float* __restrict__ bias, void* __restrict__ outp)
{
    const int tid = threadIdx.x;
    const int n0 = blockIdx.x * 128;
    const int m0 = blockIdx.y * 128;
    const int lane = tid & 63, wid = tid >> 6;
    const int wm = (wid & 1) * 64, wn = (wid >> 1) * 64;

    __shared__ unsigned short As[128][40];
    __shared__ unsigned short Ws[128][40];

    f32x4 acc[4][4];
#pragma unroll
    for (int i = 0; i < 4; ++i)
#pragma unroll
        for (int j = 0; j < 4; ++j) acc[i][j] = (f32x4){0.f, 0.f, 0.f, 0.f};

    const int srow = tid >> 1, sseg = (tid & 1) * 16;
    const unsigned short* gA = &A[(size_t)(m0 + srow) * DDIM + sseg];
    const unsigned short* gW = &W[(size_t)(n0 + srow) * DDIM + sseg];
    const int frow = lane & 15, fk = (lane >> 4) * 8;

    for (int k0 = 0; k0 < DDIM; k0 += 32) {
        uint4 a0 = *(const uint4*)(gA + k0);
        uint4 a1 = *(const uint4*)(gA + k0 + 8);
        uint4 w0 = *(const uint4*)(gW + k0);
        uint4 w1 = *(const uint4*)(gW + k0 + 8);
        __syncthreads();
        *(uint4*)&As[srow][sseg]     = a0;
        *(uint4*)&As[srow][sseg + 8] = a1;
        *(uint4*)&Ws[srow][sseg]     = w0;
        *(uint4*)&Ws[srow][sseg + 8] = w1;
        __syncthreads();
        short8 af[4], wf[4];
#pragma unroll
        for (int mi = 0; mi < 4; ++mi)
            af[mi] = *(const short8*)&As[wm + mi * 16 + frow][fk];
#pragma unroll
        for (int ni = 0; ni < 4; ++ni)
            wf[ni] = *(const short8*)&Ws[wn + ni * 16 + frow][fk];
#pragma unroll
        for (int mi = 0; mi < 4; ++mi)
#pragma unroll
            for (int ni = 0; ni < 4; ++ni)
                acc[mi][ni] = __builtin_amdgcn_mfma_f32_16x16x32_bf16(
                    af[mi], wf[ni], acc[mi][ni], 0, 0, 0);
    }

#pragma unroll
    for (int mi = 0; mi < 4; ++mi) {
#pragma unroll
        for (int ni = 0; ni < 4; ++ni) {
            const int n = n0 + wn + ni * 16 + (lane & 15);
#pragma unroll
            for (int r = 0; r < 4; ++r) {
                const int m = m0 + wm + mi * 16 + (lane >> 4) * 4 + r;
                const float v = acc[mi][ni][r] + bias[n];
                if (MODE == 1) {
                    ((float*)outp)[(size_t)m * DDIM + n] = v;
                } else {
                    ((unsigned short*)outp)[(size_t)m * DDIM + n] = f2bf(gelu_exact(v));
                }
            }
        }
    }
}

// ---------------------------------------------------------------------------
// Attention v4: no LDS staging, no barriers in the MFMA loops.
// Block = (slate, head, batch), 4 waves.
// QK^T: wave w owns keys t0+w*16..+15; K B-frags loaded directly from global.
// Softmax: wave per row; P -> bf16 in place.
// PV: wave w owns dims w*16..+15; V^T B-frags loaded directly from global.
// ---------------------------------------------------------------------------
__global__ __launch_bounds__(256) void attn_mfma(
    const unsigned short* __restrict__ qx, const unsigned short* __restrict__ kx,
    const unsigned short* __restrict__ vt, const int* __restrict__ resp,
    unsigned short* __restrict__ outb)
{
    const int s0 = blockIdx.x, h = blockIdx.y, b = blockIdx.z;
    const int tid = threadIdx.x, lane = tid & 63, w = tid >> 6;
    const int nk = s0 * KPS + 1;
    const int NT = (nk + 63) >> 6;
    const int NK = NT << 6;            // <= 512

    __shared__ float scf[KPS][516];    // rows become bf16 P in place
    __shared__ float invb[KPS];

    const int frow = lane & 15, fk = (lane >> 4) * 8;
    const size_t bh = (size_t)b * HEADS + h;
    const unsigned short* kbase = kx + bh * LFULL * HD;
    const unsigned short* vbase = vt + bh * HD * LFULL;   // [d][l]

    // Q fragments
    short8 qf[2][2];
#pragma unroll
    for (int mi = 0; mi < 2; ++mi) {
        const int qrow = mi * 16 + frow;
#pragma unroll
        for (int ks = 0; ks < 2; ++ks) {
            short8 v = {};
            if (qrow < KPS)
                v = *(const short8*)&qx[(bh * LFULL + s0 * KPS + 1 + qrow) * HD
                                        + ks * 32 + fk];
            qf[mi][ks] = v;
        }
    }

    // ---- QK^T (barrier-free) ----
    for (int t = 0; t < NT; ++t) {
        const int t0 = t << 6;
        const int key = t0 + w * 16 + frow;
        const unsigned short* kr = kbase + (size_t)key * HD;
        const short8 kf0 = *(const short8*)(kr + fk);
        const short8 kf1 = *(const short8*)(kr + 32 + fk);
        f32x4 s2[2];
#pragma unroll
        for (int mi = 0; mi < 2; ++mi) {
            s2[mi] = (f32x4){0.f, 0.f, 0.f, 0.f};
            s2[mi] = __builtin_amdgcn_mfma_f32_16x16x32_bf16(qf[mi][0], kf0, s2[mi], 0, 0, 0);
            s2[mi] = __builtin_amdgcn_mfma_f32_16x16x32_bf16(qf[mi][1], kf1, s2[mi], 0, 0, 0);
        }
        const bool allow = (key == 0) || (key < nk && resp[(size_t)b * NROWS + key - 1] > 0);
#pragma unroll
        for (int mi = 0; mi < 2; ++mi)
#pragma unroll
            for (int r = 0; r < 4; ++r) {
                const int row = mi * 16 + (lane >> 4) * 4 + r;
                if (row < KPS)
                    scf[row][key] = allow ? s2[mi][r] * 0.125f : -1e30f;
            }
    }
    __syncthreads();

    // ---- softmax (wave per row), bf16 P in place ----
    for (int r = w; r < KPS; r += 4) {
        float xv[8];
        float mx = -1e30f;
#pragma unroll
        for (int i = 0; i < 8; ++i) {
            const int k_ = lane + i * 64;
            if (k_ < NK) { xv[i] = scf[r][k_]; mx = fmaxf(mx, xv[i]); }
        }
#pragma unroll
        for (int off = 32; off; off >>= 1) mx = fmaxf(mx, __shfl_xor(mx, off, 64));
        float ss = 0.f;
        unsigned short* pr = (unsigned short*)&scf[r][0];
#pragma unroll
        for (int i = 0; i < 8; ++i) {
            const int k_ = lane + i * 64;
            if (k_ < NK) {
                const float p = __expf(xv[i] - mx);
                ss += p;
                pr[k_] = f2bf(p);
            }
        }
#pragma unroll
        for (int off = 32; off; off >>= 1) ss += __shfl_xor(ss, off, 64);
        if (lane == 0) invb[r] = 1.0f / ss;
    }
    __syncthreads();

    // ---- PV (barrier-free; wave w owns dims w*16..w*16+15) ----
    f32x4 po[2];
    po[0] = (f32x4){0.f, 0.f, 0.f, 0.f};
    po[1] = (f32x4){0.f, 0.f, 0.f, 0.f};
    const unsigned short* vrow = vbase + (size_t)(w * 16 + frow) * LFULL;
    for (int t = 0; t < NT; ++t) {
        const int t0 = t << 6;
#pragma unroll
        for (int ks = 0; ks < 2; ++ks) {
            const short8 vf = *(const short8*)(vrow + t0 + ks * 32 + fk);
#pragma unroll
            for (int mi = 0; mi < 2; ++mi) {
                short8 pf = {};
                const int prow = mi * 16 + frow;
                if (prow < KPS)
                    pf = *(const short8*)((const unsigned short*)&scf[prow][0]
                                          + t0 + ks * 32 + fk);
                po[mi] = __builtin_amdgcn_mfma_f32_16x16x32_bf16(pf, vf, po[mi], 0, 0, 0);
            }
        }
    }

#pragma unroll
    for (int mi = 0; mi < 2; ++mi)
#pragma unroll
        for (int r = 0; r < 4; ++r) {
            const int row = mi * 16 + (lane >> 4) * 4 + r;
            if (row < KPS)
                outb[((size_t)b * NROWS + s0 * KPS + row) * DDIM
                     + h * HD + w * 16 + frow] = f2bf(po[mi][r] * invb[row]);
        }
}

// ---------------------------------------------------------------------------
// LayerNorm fp32 -> bf16. One wave per row.
// ---------------------------------------------------------------------------
__global__ __launch_bounds__(256) void ln_kernel(
    const float* __restrict__ f, const float* __restrict__ g,
    const float* __restrict__ bt, unsigned short* __restrict__ o)
{
    const int row = blockIdx.x * 4 + (threadIdx.x >> 6);
    const int lane = threadIdx.x & 63;
    const float* fr = f + (size_t)row * DDIM;
    float xv[8];
    float s = 0.f;
#pragma unroll
    for (int i = 0; i < 8; ++i) { xv[i] = fr[lane + i * 64]; s += xv[i]; }
#pragma unroll
    for (int off = 32; off; off >>= 1) s += __shfl_xor(s, off, 64);
    const float mu = s * (1.0f / DDIM);
    float var = 0.f;
#pragma unroll
    for (int i = 0; i < 8; ++i) { const float d0 = xv[i] - mu; var += d0 * d0; }
#pragma unroll
    for (int off = 32; off; off >>= 1) var += __shfl_xor(var, off, 64);
    const float rs = rsqrtf(var * (1.0f / DDIM) + 1e-5f);
#pragma unroll
    for (int i = 0; i < 8; ++i) {
        const int d0 = lane + i * 64;
        o[(size_t)row * DDIM + d0] = f2bf((xv[i] - mu) * rs * g[d0] + bt[d0]);
    }
}

// ---------------------------------------------------------------------------
// Final head.
// ---------------------------------------------------------------------------
__global__ __launch_bounds__(256) void w2_kernel(
    const unsigned short* __restrict__ h, const float* __restrict__ W2,
    const float* __restrict__ b2, float* __restrict__ out)
{
    const int row = blockIdx.x * 4 + (threadIdx.x >> 6);
    const int lane = threadIdx.x & 63;
    float s = 0.f;
#pragma unroll
    for (int i = 0; i < 8; ++i) {
        const int d = lane + i * 64;
        s += bf2f(h[(size_t)row * DDIM + d]) * W2[d];
    }
#pragma unroll
    for (int off = 32; off; off >>= 1) s += __shfl_xor(s, off, 64);
    if (lane == 0) out[row] = s + b2[0];
}

// ---------------------------------------------------------------------------
extern "C" void kernel_launch(void* const* d_in, const int* in_sizes, int n_in,
                              void* d_out, int out_size, void* d_ws, size_t ws_size,
                              hipStream_t stream)
{
    const float* item = (const float*)d_in[0];
    const float* user = (const float*)d_in[1];
    const int*   resp = (const int*)d_in[2];
    const float* Wq = (const float*)d_in[3];  const float* bq = (const float*)d_in[4];
    const float* Wk = (const float*)d_in[5];  const float* bk = (const float*)d_in[6];
    const float* Wv = (const float*)d_in[7];  const float* bv = (const float*)d_in[8];
    const float* Wo = (const float*)d_in[9];  const float* bo = (const float*)d_in[10];
    const float* lng = (const float*)d_in[11]; const float* lnb = (const float*)d_in[12];
    const float* W1 = (const float*)d_in[13]; const float* b1 = (const float*)d_in[14];
    const float* W2 = (const float*)d_in[15]; const float* b2 = (const float*)d_in[16];
    float* out = (float*)d_out;

    char* p = (char*)d_ws;
    auto alloc = [&](size_t bytes) { char* r = p; p += (bytes + 255) & ~(size_t)255; return r; };
    const size_t NITEM = (size_t)BATCH * NROWS * EDIM;
    const size_t NW    = (size_t)DDIM * DDIM;
    const size_t NQKV  = (size_t)BATCH * HEADS * LFULL * HD;
    const size_t NMD   = (size_t)MTOT * DDIM;
    const size_t PAD   = 8192;   // absorb OOB tile reads (masked / P=0)

    unsigned short* itemb = (unsigned short*)alloc(NITEM * 2);
    unsigned short* Wqb = (unsigned short*)alloc(NW * 2);
    unsigned short* Wkb = (unsigned short*)alloc(NW * 2);
    unsigned short* Wvb = (unsigned short*)alloc(NW * 2);
    unsigned short* Wob = (unsigned short*)alloc(NW * 2);
    unsigned short* W1b = (unsigned short*)alloc(NW * 2);
    unsigned short* qb  = (unsigned short*)alloc(NQKV * 2 + PAD);
    unsigned short* kb  = (unsigned short*)alloc(NQKV * 2 + PAD);
    unsigned short* vtb = (unsigned short*)alloc(NQKV * 2 + PAD);
    unsigned short* aob = (unsigned short*)alloc(NMD * 2);
    unsigned short* hb  = (unsigned short*)alloc(NMD * 2);
    float* fbuf = (float*)alloc(NMD * 4);
    float* ubq  = (float*)alloc((size_t)BATCH * DDIM * 4);
    float* ubk  = (float*)alloc((size_t)BATCH * DDIM * 4);
    float* ubv  = (float*)alloc((size_t)BATCH * DDIM * 4);

    cvt_kernel<<<dim3((NITEM / 4 + 255) / 256), 256, 0, stream>>>(item, itemb, NITEM / 4);
    Cvt5 c5;
    c5.s[0] = Wq; c5.s[1] = Wk; c5.s[2] = Wv; c5.s[3] = Wo; c5.s[4] = W1;
    c5.d[0] = Wqb; c5.d[1] = Wkb; c5.d[2] = Wvb; c5.d[3] = Wob; c5.d[4] = W1b;
    cvt5_kernel<<<dim3(NW / 4 / 256, 5), 256, 0, stream>>>(c5, NW / 4);

    user_bias_kernel<<<dim3(BATCH, 3), 256, 0, stream>>>(
        user, Wq, bq, Wk, bk, Wv, bv, ubq, ubk, ubv, qb, kb, vtb);

    dim3 gq(DDIM / 128, MTOT / 128, 3);
    gemm_qkv<<<gq, 256, 0, stream>>>(itemb, Wqb, Wkb, Wvb, ubq, ubk, ubv, qb, kb, vtb);

    attn_mfma<<<dim3(SLATES, HEADS, BATCH), 256, 0, stream>>>(qb, kb, vtb, resp, aob);

    dim3 gg(DDIM / 128, MTOT / 128);
    gemm_bf16<1><<<gg, 256, 0, stream>>>(aob, Wob, bo, fbuf);
    ln_kernel<<<dim3(MTOT / 4), 256, 0, stream>>>(fbuf, lng, lnb, aob);
    gemm_bf16<2><<<gg, 256, 0, stream>>>(aob, W1b, b1, hb);
    w2_kernel<<<dim3(MTOT / 4), 256, 0, stream>>>(hb, W2, b2, out);
}

// Round 5
// 342.070 us; speedup vs baseline: 1.3882x; 1.3882x over previous
//
#include <hip/hip_runtime.h>
#include <math.h>

#define BATCH 64
#define SLATES 25
#define KPS 20
#define EDIM 256
#define DDIM 512
#define HEADS 8
#define HD 64
#define LFULL 501
#define NROWS 500
#define MTOT (BATCH*NROWS)   // 32000
#define CMAX 512             // compacted key capacity (max 501)

typedef __attribute__((ext_vector_type(8))) short short8;
typedef __attribute__((ext_vector_type(4))) float f32x4;

__device__ __forceinline__ unsigned short f2bf(float x) {
    unsigned int u = __builtin_bit_cast(unsigned int, x);
    u = (u + 0x7FFFu + ((u >> 16) & 1u)) >> 16;
    return (unsigned short)u;
}
__device__ __forceinline__ float bf2f(unsigned short s) {
    unsigned int u = ((unsigned int)s) << 16;
    return __builtin_bit_cast(float, u);
}
__device__ __forceinline__ float gelu_exact(float x) {
    return 0.5f * x * (1.0f + erff(x * 0.70710678118654752440f));
}
__device__ __forceinline__ void gload16(const void* g, void* l) {
    __builtin_amdgcn_global_load_lds(
        (const __attribute__((address_space(1))) void*)g,
        (__attribute__((address_space(3))) void*)l, 16, 0, 0);
}

// ---------------------------------------------------------------------------
// fp32 -> bf16 converts
// ---------------------------------------------------------------------------
__global__ __launch_bounds__(256) void cvt_kernel(
    const float* __restrict__ src, unsigned short* __restrict__ dst, int n4)
{
    const int i = blockIdx.x * 256 + threadIdx.x;
    if (i >= n4) return;
    float4 v = ((const float4*)src)[i];
    ushort4 o;
    o.x = f2bf(v.x); o.y = f2bf(v.y); o.z = f2bf(v.z); o.w = f2bf(v.w);
    ((ushort4*)dst)[i] = o;
}

struct Cvt5 { const float* s[5]; unsigned short* d[5]; };
__global__ __launch_bounds__(256) void cvt5_kernel(Cvt5 a, int n4)
{
    const int i = blockIdx.x * 256 + threadIdx.x;
    if (i >= n4) return;
    const int y = blockIdx.y;
    float4 v = ((const float4*)a.s[y])[i];
    ushort4 o;
    o.x = f2bf(v.x); o.y = f2bf(v.y); o.z = f2bf(v.z); o.w = f2bf(v.w);
    ((ushort4*)a.d[y])[i] = o;
}

// ---------------------------------------------------------------------------
// Click compaction: one wave per batch. cidx[b][l] = compacted position of
// allowed key l (or -1); cnt[b][s] = #allowed keys with index < s*20+1.
// ---------------------------------------------------------------------------
__global__ __launch_bounds__(64) void compact_kernel(
    const int* __restrict__ resp, int* __restrict__ cidx, int* __restrict__ cnt)
{
    const int b = blockIdx.x, lane = threadIdx.x;
    int a[8]; int c = 0;
#pragma unroll
    for (int j = 0; j < 8; ++j) {
        const int l = lane * 8 + j;
        int al = 0;
        if (l == 0) al = 1;
        else if (l <= NROWS) al = (resp[(size_t)b * NROWS + l - 1] > 0) ? 1 : 0;
        a[j] = al; c += al;
    }
    int incl = c;
#pragma unroll
    for (int off = 1; off < 64; off <<= 1) {
        int t = __shfl_up(incl, off, 64);
        if (lane >= off) incl += t;
    }
    int run = incl - c;   // exclusive prefix
#pragma unroll
    for (int j = 0; j < 8; ++j) {
        const int l = lane * 8 + j;
        if (l >= 1 && l <= 481 && (l % 20) == 1)
            cnt[b * 32 + (l - 1) / 20] = run;
        cidx[b * 512 + l] = a[j] ? run : -1;
        run += a[j];
    }
}

// ---------------------------------------------------------------------------
// Per-batch user-projection bias tables (fp32) + position-0 rows of q
// (head-major), K^c, and V^cT (key 0 is always compacted position 0).
// ---------------------------------------------------------------------------
__global__ __launch_bounds__(256) void user_bias_kernel(
    const float* __restrict__ user,
    const float* __restrict__ Wq, const float* __restrict__ bq,
    const float* __restrict__ Wk, const float* __restrict__ bk,
    const float* __restrict__ Wv, const float* __restrict__ bv,
    float* __restrict__ ubq, float* __restrict__ ubk, float* __restrict__ ubv,
    unsigned short* __restrict__ qb, unsigned short* __restrict__ kc,
    unsigned short* __restrict__ vc)
{
    const int b = blockIdx.x;
    const int y = blockIdx.y;
    const int tid = threadIdx.x;
    const float* W  = (y == 0) ? Wq : (y == 1) ? Wk : Wv;
    const float* bi = (y == 0) ? bq : (y == 1) ? bk : bv;
    float* ub = (y == 0) ? ubq : (y == 1) ? ubk : ubv;

    __shared__ float us[EDIM];
    if (tid < EDIM) us[tid] = user[b * EDIM + tid];
    __syncthreads();
    for (int o = tid; o < DDIM; o += 256) {
        float s = bi[o];
        const float* wr = &W[(size_t)o * DDIM + EDIM];
#pragma unroll 4
        for (int e = 0; e < EDIM; ++e) s += us[e] * wr[e];
        ub[b * DDIM + o] = s;
        const int hh = o >> 6, dd = o & 63;
        const size_t bh = (size_t)b * HEADS + hh;
        if (y == 0)      qb[(bh * LFULL) * HD + dd] = f2bf(bi[o]);
        else if (y == 1) kc[(bh * CMAX) * HD + dd] = f2bf(bi[o]);
        else             vc[(bh * HD + dd) * CMAX] = f2bf(bi[o]);
    }
}

// ---------------------------------------------------------------------------
// Fused QKV GEMM with global_load_lds staging (m97 structure).
// q out: head-major (B,H,501,64) at l=m%500+1.
// k out: compacted (B,H,CMAX,64) at c=cidx[b][l] (skip if -1).
// v out: compacted transposed (B,H,64,CMAX) at col c.
// ---------------------------------------------------------------------------
__global__ __launch_bounds__(256) void gemm_qkv(
    const unsigned short* __restrict__ A,
    const unsigned short* __restrict__ Wq, const unsigned short* __restrict__ Wk,
    const unsigned short* __restrict__ Wv,
    const float* __restrict__ uq, const float* __restrict__ uk,
    const float* __restrict__ uv, const int* __restrict__ cidx,
    unsigned short* __restrict__ oq, unsigned short* __restrict__ ok,
    unsigned short* __restrict__ ov)
{
    const int z = blockIdx.z;
    const unsigned short* W = (z == 0) ? Wq : (z == 1) ? Wk : Wv;
    const float* ub = (z == 0) ? uq : (z == 1) ? uk : uv;

    const int tid = threadIdx.x;
    const int n0 = blockIdx.x * 128;
    const int m0 = blockIdx.y * 128;
    const int lane = tid & 63, wid = tid >> 6;
    const int wm = (wid & 1) * 64, wn = (wid >> 1) * 64;

    __shared__ unsigned short As[128][32];
    __shared__ unsigned short Ws[128][32];

    f32x4 acc[4][4];
#pragma unroll
    for (int i = 0; i < 4; ++i)
#pragma unroll
        for (int j = 0; j < 4; ++j) acc[i][j] = (f32x4){0.f, 0.f, 0.f, 0.f};

    const int lrow = lane >> 2, lseg = (lane & 3) * 8;
    const unsigned short* gA0 = &A[(size_t)(m0 + wid * 16 + lrow) * EDIM + lseg];
    const unsigned short* gA1 = gA0 + (size_t)64 * EDIM;
    const unsigned short* gW0 = &W[(size_t)(n0 + wid * 16 + lrow) * DDIM + lseg];
    const unsigned short* gW1 = gW0 + (size_t)64 * DDIM;
    unsigned short* lA0 = &As[wid * 16][0];
    unsigned short* lA1 = &As[64 + wid * 16][0];
    unsigned short* lW0 = &Ws[wid * 16][0];
    unsigned short* lW1 = &Ws[64 + wid * 16][0];
    const int frow = lane & 15, fk = (lane >> 4) * 8;

    for (int k0 = 0; k0 < EDIM; k0 += 32) {
        if (k0) __syncthreads();
        gload16(gA0 + k0, lA0);
        gload16(gA1 + k0, lA1);
        gload16(gW0 + k0, lW0);
        gload16(gW1 + k0, lW1);
        __syncthreads();
        short8 af[4], wf[4];
#pragma unroll
        for (int mi = 0; mi < 4; ++mi)
            af[mi] = *(const short8*)&As[wm + mi * 16 + frow][fk];
#pragma unroll
        for (int ni = 0; ni < 4; ++ni)
            wf[ni] = *(const short8*)&Ws[wn + ni * 16 + frow][fk];
#pragma unroll
        for (int mi = 0; mi < 4; ++mi)
#pragma unroll
            for (int ni = 0; ni < 4; ++ni)
                acc[mi][ni] = __builtin_amdgcn_mfma_f32_16x16x32_bf16(
                    af[mi], wf[ni], acc[mi][ni], 0, 0, 0);
    }

#pragma unroll
    for (int mi = 0; mi < 4; ++mi) {
#pragma unroll
        for (int ni = 0; ni < 4; ++ni) {
            const int n = n0 + wn + ni * 16 + (lane & 15);
            const int hh = n >> 6, dd = n & 63;
#pragma unroll
            for (int r = 0; r < 4; ++r) {
                const int m = m0 + wm + mi * 16 + (lane >> 4) * 4 + r;
                const int b = m / NROWS;
                const int l = m - b * NROWS + 1;
                const size_t bh = (size_t)b * HEADS + hh;
                const float v = acc[mi][ni][r] + ub[(size_t)b * DDIM + n];
                if (z == 0) {
                    oq[(bh * LFULL + l) * HD + dd] = f2bf(v);
                } else {
                    const int c = cidx[b * 512 + l];
                    if (c >= 0) {
                        if (z == 1) ok[(bh * CMAX + c) * HD + dd] = f2bf(v);
                        else        ov[(bh * HD + dd) * CMAX + c] = f2bf(v);
                    }
                }
            }
        }
    }
}

// ---------------------------------------------------------------------------
// Generic bf16 GEMM (global_load_lds staging).
// MODE 1: +bias, fp32 out. MODE 2: +bias + gelu, bf16 out.
// ---------------------------------------------------------------------------
template <int MODE>
__global__ __launch_bounds__(256) void gemm_bf16(
    const unsigned short* __restrict__ A,
    const unsigned short* __restrict__ W,
    const float* __restrict__ bias, void* __restrict__ outp)
{
    const int tid = threadIdx.x;
    const int n0 = blockIdx.x * 128;
    const int m0 = blockIdx.y * 128;
    const int lane = tid & 63, wid = tid >> 6;
    const int wm = (wid & 1) * 64, wn = (wid >> 1) * 64;

    __shared__ unsigned short As[128][32];
    __shared__ unsigned short Ws[128][32];

    f32x4 acc[4][4];
#pragma unroll
    for (int i = 0; i < 4; ++i)
#pragma unroll
        for (int j = 0; j < 4; ++j) acc[i][j] = (f32x4){0.f, 0.f, 0.f, 0.f};

    const int lrow = lane >> 2, lseg = (lane & 3) * 8;
    const unsigned short* gA0 = &A[(size_t)(m0 + wid * 16 + lrow) * DDIM + lseg];
    const unsigned short* gA1 = gA0 + (size_t)64 * DDIM;
    const unsigned short* gW0 = &W[(size_t)(n0 + wid * 16 + lrow) * DDIM + lseg];
    const unsigned short* gW1 = gW0 + (size_t)64 * DDIM;
    unsigned short* lA0 = &As[wid * 16][0];
    unsigned short* lA1 = &As[64 + wid * 16][0];
    unsigned short* lW0 = &Ws[wid * 16][0];
    unsigned short* lW1 = &Ws[64 + wid * 16][0];
    const int frow = lane & 15, fk = (lane >> 4) * 8;

    for (int k0 = 0; k0 < DDIM; k0 += 32) {
        if (k0) __syncthreads();
        gload16(gA0 + k0, lA0);
        gload16(gA1 + k0, lA1);
        gload16(gW0 + k0, lW0);
        gload16(gW1 + k0, lW1);
        __syncthreads();
        short8 af[4], wf[4];
#pragma unroll
        for (int mi = 0; mi < 4; ++mi)
            af[mi] = *(const short8*)&As[wm + mi * 16 + frow][fk];
#pragma unroll
        for (int ni = 0; ni < 4; ++ni)
            wf[ni] = *(const short8*)&Ws[wn + ni * 16 + frow][fk];
#pragma unroll
        for (int mi = 0; mi < 4; ++mi)
#pragma unroll
            for (int ni = 0; ni < 4; ++ni)
                acc[mi][ni] = __builtin_amdgcn_mfma_f32_16x16x32_bf16(
                    af[mi], wf[ni], acc[mi][ni], 0, 0, 0);
    }

#pragma unroll
    for (int mi = 0; mi < 4; ++mi) {
#pragma unroll
        for (int ni = 0; ni < 4; ++ni) {
            const int n = n0 + wn + ni * 16 + (lane & 15);
#pragma unroll
            for (int r = 0; r < 4; ++r) {
                const int m = m0 + wm + mi * 16 + (lane >> 4) * 4 + r;
                const float v = acc[mi][ni][r] + bias[n];
                if (MODE == 1) {
                    ((float*)outp)[(size_t)m * DDIM + n] = v;
                } else {
                    ((unsigned short*)outp)[(size_t)m * DDIM + n] = f2bf(gelu_exact(v));
                }
            }
        }
    }
}

// ---------------------------------------------------------------------------
// Attention v5: compacted keys, bf16 score LDS (21 KB -> 7 blocks/CU),
// no LDS staging, no barriers in MFMA loops, mask = index compare.
// ---------------------------------------------------------------------------
__global__ __launch_bounds__(256) void attn_mfma(
    const unsigned short* __restrict__ qx, const unsigned short* __restrict__ kc,
    const unsigned short* __restrict__ vc, const int* __restrict__ cnt,
    unsigned short* __restrict__ outb)
{
    const int s0 = blockIdx.x, h = blockIdx.y, b = blockIdx.z;
    const int tid = threadIdx.x, lane = tid & 63, w = tid >> 6;
    const int nck = cnt[b * 32 + s0];          // >= 1 (key 0 always allowed)
    const int NT = (nck + 63) >> 6;
    const int NK = NT << 6;                    // <= 512

    __shared__ __align__(16) unsigned short scb[KPS][520];  // bf16 scores / P
    __shared__ float invb[KPS];

    const int frow = lane & 15, fk = (lane >> 4) * 8;
    const size_t bh = (size_t)b * HEADS + h;
    const unsigned short* kbase = kc + bh * (CMAX * HD);
    const unsigned short* vbase = vc + bh * (HD * CMAX);

    // Q fragments
    short8 qf[2][2];
#pragma unroll
    for (int mi = 0; mi < 2; ++mi) {
        const int qrow = mi * 16 + frow;
#pragma unroll
        for (int ks = 0; ks < 2; ++ks) {
            short8 v = {};
            if (qrow < KPS)
                v = *(const short8*)&qx[(bh * LFULL + s0 * KPS + 1 + qrow) * HD
                                        + ks * 32 + fk];
            qf[mi][ks] = v;
        }
    }

    // ---- QK^T (barrier-free; wave w owns keys t0+w*16..+15) ----
    for (int t = 0; t < NT; ++t) {
        const int key = (t << 6) + w * 16 + frow;
        const unsigned short* kr = kbase + (size_t)key * HD;
        const short8 kf0 = *(const short8*)(kr + fk);
        const short8 kf1 = *(const short8*)(kr + 32 + fk);
        f32x4 s2[2];
#pragma unroll
        for (int mi = 0; mi < 2; ++mi) {
            s2[mi] = (f32x4){0.f, 0.f, 0.f, 0.f};
            s2[mi] = __builtin_amdgcn_mfma_f32_16x16x32_bf16(qf[mi][0], kf0, s2[mi], 0, 0, 0);
            s2[mi] = __builtin_amdgcn_mfma_f32_16x16x32_bf16(qf[mi][1], kf1, s2[mi], 0, 0, 0);
        }
        const bool allow = key < nck;
#pragma unroll
        for (int mi = 0; mi < 2; ++mi)
#pragma unroll
            for (int r = 0; r < 4; ++r) {
                const int row = mi * 16 + (lane >> 4) * 4 + r;
                if (row < KPS)
                    scb[row][key] = f2bf(allow ? s2[mi][r] * 0.125f : -1e30f);
            }
    }
    __syncthreads();

    // ---- softmax (wave per row), bf16 P in place ----
    for (int r = w; r < KPS; r += 4) {
        float xv[8];
        float mx = -1e30f;
#pragma unroll
        for (int i = 0; i < 8; ++i) {
            const int k_ = lane + i * 64;
            if (k_ < NK) { xv[i] = bf2f(scb[r][k_]); mx = fmaxf(mx, xv[i]); }
        }
#pragma unroll
        for (int off = 32; off; off >>= 1) mx = fmaxf(mx, __shfl_xor(mx, off, 64));
        float ss = 0.f;
#pragma unroll
        for (int i = 0; i < 8; ++i) {
            const int k_ = lane + i * 64;
            if (k_ < NK) {
                const float p = __expf(xv[i] - mx);
                ss += p;
                scb[r][k_] = f2bf(p);
            }
        }
#pragma unroll
        for (int off = 32; off; off >>= 1) ss += __shfl_xor(ss, off, 64);
        if (lane == 0) invb[r] = 1.0f / ss;
    }
    __syncthreads();

    // ---- PV (barrier-free; wave w owns dims w*16..w*16+15) ----
    f32x4 po[2];
    po[0] = (f32x4){0.f, 0.f, 0.f, 0.f};
    po[1] = (f32x4){0.f, 0.f, 0.f, 0.f};
    const unsigned short* vrow = vbase + (size_t)(w * 16 + frow) * CMAX;
    for (int t = 0; t < NT; ++t) {
#pragma unroll
        for (int ks = 0; ks < 2; ++ks) {
            const int kb0 = (t << 6) + ks * 32 + fk;
            short8 vf;
            if (t + 1 < NT) {
                vf = *(const short8*)(vrow + kb0);
            } else if (kb0 + 8 <= nck) {
                vf = *(const short8*)(vrow + kb0);
            } else {
#pragma unroll
                for (int j = 0; j < 8; ++j)
                    vf[j] = (kb0 + j < nck) ? (short)vrow[kb0 + j] : (short)0;
            }
#pragma unroll
            for (int mi = 0; mi < 2; ++mi) {
                short8 pf = {};
                const int prow = mi * 16 + frow;
                if (prow < KPS)
                    pf = *(const short8*)&scb[prow][kb0];
                po[mi] = __builtin_amdgcn_mfma_f32_16x16x32_bf16(pf, vf, po[mi], 0, 0, 0);
            }
        }
    }

#pragma unroll
    for (int mi = 0; mi < 2; ++mi)
#pragma unroll
        for (int r = 0; r < 4; ++r) {
            const int row = mi * 16 + (lane >> 4) * 4 + r;
            if (row < KPS)
                outb[((size_t)b * NROWS + s0 * KPS + row) * DDIM
                     + h * HD + w * 16 + frow] = f2bf(po[mi][r] * invb[row]);
        }
}

// ---------------------------------------------------------------------------
// LayerNorm fp32 -> bf16. One wave per row.
// ---------------------------------------------------------------------------
__global__ __launch_bounds__(256) void ln_kernel(
    const float* __restrict__ f, const float* __restrict__ g,
    const float* __restrict__ bt, unsigned short* __restrict__ o)
{
    const int row = blockIdx.x * 4 + (threadIdx.x >> 6);
    const int lane = threadIdx.x & 63;
    const float* fr = f + (size_t)row * DDIM;
    float xv[8];
    float s = 0.f;
#pragma unroll
    for (int i = 0; i < 8; ++i) { xv[i] = fr[lane + i * 64]; s += xv[i]; }
#pragma unroll
    for (int off = 32; off; off >>= 1) s += __shfl_xor(s, off, 64);
    const float mu = s * (1.0f / DDIM);
    float var = 0.f;
#pragma unroll
    for (int i = 0; i < 8; ++i) { const float d0 = xv[i] - mu; var += d0 * d0; }
#pragma unroll
    for (int off = 32; off; off >>= 1) var += __shfl_xor(var, off, 64);
    const float rs = rsqrtf(var * (1.0f / DDIM) + 1e-5f);
#pragma unroll
    for (int i = 0; i < 8; ++i) {
        const int d0 = lane + i * 64;
        o[(size_t)row * DDIM + d0] = f2bf((xv[i] - mu) * rs * g[d0] + bt[d0]);
    }
}

// ---------------------------------------------------------------------------
// Final head.
// ---------------------------------------------------------------------------
__global__ __launch_bounds__(256) void w2_kernel(
    const unsigned short* __restrict__ h, const float* __restrict__ W2,
    const float* __restrict__ b2, float* __restrict__ out)
{
    const int row = blockIdx.x * 4 + (threadIdx.x >> 6);
    const int lane = threadIdx.x & 63;
    float s = 0.f;
#pragma unroll
    for (int i = 0; i < 8; ++i) {
        const int d = lane + i * 64;
        s += bf2f(h[(size_t)row * DDIM + d]) * W2[d];
    }
#pragma unroll
    for (int off = 32; off; off >>= 1) s += __shfl_xor(s, off, 64);
    if (lane == 0) out[row] = s + b2[0];
}

// ---------------------------------------------------------------------------
extern "C" void kernel_launch(void* const* d_in, const int* in_sizes, int n_in,
                              void* d_out, int out_size, void* d_ws, size_t ws_size,
                              hipStream_t stream)
{
    const float* item = (const float*)d_in[0];
    const float* user = (const float*)d_in[1];
    const int*   resp = (const int*)d_in[2];
    const float* Wq = (const float*)d_in[3];  const float* bq = (const float*)d_in[4];
    const float* Wk = (const float*)d_in[5];  const float* bk = (const float*)d_in[6];
    const float* Wv = (const float*)d_in[7];  const float* bv = (const float*)d_in[8];
    const float* Wo = (const float*)d_in[9];  const float* bo = (const float*)d_in[10];
    const float* lng = (const float*)d_in[11]; const float* lnb = (const float*)d_in[12];
    const float* W1 = (const float*)d_in[13]; const float* b1 = (const float*)d_in[14];
    const float* W2 = (const float*)d_in[15]; const float* b2 = (const float*)d_in[16];
    float* out = (float*)d_out;

    char* p = (char*)d_ws;
    auto alloc = [&](size_t bytes) { char* r = p; p += (bytes + 255) & ~(size_t)255; return r; };
    const size_t NITEM = (size_t)BATCH * NROWS * EDIM;
    const size_t NW    = (size_t)DDIM * DDIM;
    const size_t NQ    = (size_t)BATCH * HEADS * LFULL * HD;
    const size_t NC    = (size_t)BATCH * HEADS * CMAX * HD;
    const size_t NMD   = (size_t)MTOT * DDIM;
    const size_t PAD   = 8192;

    unsigned short* itemb = (unsigned short*)alloc(NITEM * 2);
    unsigned short* Wqb = (unsigned short*)alloc(NW * 2);
    unsigned short* Wkb = (unsigned short*)alloc(NW * 2);
    unsigned short* Wvb = (unsigned short*)alloc(NW * 2);
    unsigned short* Wob = (unsigned short*)alloc(NW * 2);
    unsigned short* W1b = (unsigned short*)alloc(NW * 2);
    unsigned short* qb  = (unsigned short*)alloc(NQ * 2 + PAD);
    unsigned short* kcb = (unsigned short*)alloc(NC * 2 + PAD);
    unsigned short* vcb = (unsigned short*)alloc(NC * 2 + PAD);
    unsigned short* aob = (unsigned short*)alloc(NMD * 2);
    unsigned short* hb  = (unsigned short*)alloc(NMD * 2);
    float* fbuf = (float*)alloc(NMD * 4);
    float* ubq  = (float*)alloc((size_t)BATCH * DDIM * 4);
    float* ubk  = (float*)alloc((size_t)BATCH * DDIM * 4);
    float* ubv  = (float*)alloc((size_t)BATCH * DDIM * 4);
    int* cidx   = (int*)alloc((size_t)BATCH * 512 * 4);
    int* cnt    = (int*)alloc((size_t)BATCH * 32 * 4);

    cvt_kernel<<<dim3((NITEM / 4 + 255) / 256), 256, 0, stream>>>(item, itemb, NITEM / 4);
    Cvt5 c5;
    c5.s[0] = Wq; c5.s[1] = Wk; c5.s[2] = Wv; c5.s[3] = Wo; c5.s[4] = W1;
    c5.d[0] = Wqb; c5.d[1] = Wkb; c5.d[2] = Wvb; c5.d[3] = Wob; c5.d[4] = W1b;
    cvt5_kernel<<<dim3(NW / 4 / 256, 5), 256, 0, stream>>>(c5, NW / 4);

    compact_kernel<<<dim3(BATCH), 64, 0, stream>>>(resp, cidx, cnt);

    user_bias_kernel<<<dim3(BATCH, 3), 256, 0, stream>>>(
        user, Wq, bq, Wk, bk, Wv, bv, ubq, ubk, ubv, qb, kcb, vcb);

    dim3 gq(DDIM / 128, MTOT / 128, 3);
    gemm_qkv<<<gq, 256, 0, stream>>>(itemb, Wqb, Wkb, Wvb, ubq, ubk, ubv, cidx,
                                     qb, kcb, vcb);

    attn_mfma<<<dim3(SLATES, HEADS, BATCH), 256, 0, stream>>>(qb, kcb, vcb, cnt, aob);

    dim3 gg(DDIM / 128, MTOT / 128);
    gemm_bf16<1><<<gg, 256, 0, stream>>>(aob, Wob, bo, fbuf);
    ln_kernel<<<dim3(MTOT / 4), 256, 0, stream>>>(fbuf, lng, lnb, aob);
    gemm_bf16<2><<<gg, 256, 0, stream>>>(aob, W1b, b1, hb);
    w2_kernel<<<dim3(MTOT / 4), 256, 0, stream>>>(hb, W2, b2, out);
}